// Round 1
// baseline (1493.471 us; speedup 1.0000x reference)
//
#include <hip/hip_runtime.h>
#include <hip/hip_bf16.h>

using bf16 = __hip_bfloat16;
typedef short v8s __attribute__((ext_vector_type(8)));
typedef float v4f __attribute__((ext_vector_type(4)));

#define NE 8
#define NT 16384
#define ND 1024
#define NH 4096
#define CAP 2048

__device__ __forceinline__ void load_lds16(const void* g, void* s) {
  __builtin_amdgcn_global_load_lds(
      (const __attribute__((address_space(1))) unsigned int*)g,
      (__attribute__((address_space(3))) unsigned int*)s, 16, 0, 0);
}

__device__ __forceinline__ float gelu_tanh(float x) {
  float u = 0.7978845608028654f * (x + 0.044715f * x * x * x);
  float e = __expf(2.0f * u);
  float t = 1.0f - 2.0f / (e + 1.0f);   // tanh(u), stable for e->0 and e->inf
  return 0.5f * x * (1.0f + t);
}

// ---------------- fp32 -> bf16 elementwise ----------------
__global__ __launch_bounds__(256) void cvt_bf16(const float* __restrict__ s,
                                                bf16* __restrict__ d, int n) {
  for (int i = (blockIdx.x * 256 + threadIdx.x) * 4; i < n; i += gridDim.x * 1024) {
    float4 v = *(const float4*)(s + i);
    bf16 o[4];
    o[0] = __float2bfloat16(v.x); o[1] = __float2bfloat16(v.y);
    o[2] = __float2bfloat16(v.z); o[3] = __float2bfloat16(v.w);
    *(ushort4*)(d + i) = *(ushort4*)o;
  }
}

// ---------------- fp32 (R,C) -> bf16 (C,R), batched over blockIdx.z ----------
__global__ __launch_bounds__(256) void tcvt(const float* __restrict__ src,
                                            bf16* __restrict__ dst, int R, int C) {
  __shared__ float tile[32][33];
  size_t mo = (size_t)blockIdx.z * R * C;
  int c0 = blockIdx.x * 32, r0 = blockIdx.y * 32;
  int tx = threadIdx.x & 31, ty = threadIdx.x >> 5;  // ty 0..7
  for (int i = ty; i < 32; i += 8)
    tile[i][tx] = src[mo + (size_t)(r0 + i) * C + c0 + tx];
  __syncthreads();
  for (int i = ty; i < 32; i += 8)
    dst[mo + (size_t)(c0 + i) * R + r0 + tx] = __float2bfloat16(tile[tx][i]);
}

// ---------------- router: logits (fp64 accum) + softmax -> probs[E][T] ------
__global__ __launch_bounds__(256) void router_k(const float* __restrict__ x,
                                                const float* __restrict__ gate,
                                                float* __restrict__ probs) {
  int wave = threadIdx.x >> 6, lane = threadIdx.x & 63;
  int t = blockIdx.x * 4 + wave;
  const float* xr = x + (size_t)t * ND;
  double acc[NE];
#pragma unroll
  for (int e = 0; e < NE; e++) acc[e] = 0.0;
  for (int d = lane; d < ND; d += 64) {
    double xv = (double)xr[d];
    const float* g = gate + d * NE;
#pragma unroll
    for (int e = 0; e < NE; e++) acc[e] += xv * (double)g[e];
  }
#pragma unroll
  for (int e = 0; e < NE; e++) {
    double v = acc[e];
#pragma unroll
    for (int off = 32; off > 0; off >>= 1) v += __shfl_xor(v, off);
    acc[e] = v;
  }
  if (lane == 0) {
    float l[NE], m = -1e30f;
#pragma unroll
    for (int e = 0; e < NE; e++) { l[e] = (float)acc[e]; m = fmaxf(m, l[e]); }
    float p[NE], s = 0.f;
#pragma unroll
    for (int e = 0; e < NE; e++) { p[e] = expf(l[e] - m); s += p[e]; }
#pragma unroll
    for (int e = 0; e < NE; e++) probs[e * NT + t] = p[e] / s;
  }
}

// ---------------- per-expert radix select of the 2048th largest prob --------
__global__ __launch_bounds__(1024) void topk_k(const float* __restrict__ probs,
                                               unsigned* __restrict__ thr_key,
                                               int* __restrict__ needed) {
  int e = blockIdx.x;
  const float* p = probs + e * NT;
  __shared__ int hist[256];
  __shared__ unsigned s_pref;
  __shared__ int s_rank;
  unsigned prefix = 0;
  int rank = CAP;  // rank-th largest (1-indexed)
  for (int rd = 0; rd < 4; rd++) {
    int shift = 24 - rd * 8;
    if (threadIdx.x < 256) hist[threadIdx.x] = 0;
    __syncthreads();
    unsigned mask = (rd == 0) ? 0u : (0xFFFFFFFFu << (shift + 8));
    for (int t = threadIdx.x; t < NT; t += 1024) {
      unsigned k = __float_as_uint(p[t]);   // probs > 0 -> uint order == float order
      if ((k & mask) == prefix) atomicAdd(&hist[(k >> shift) & 255], 1);
    }
    __syncthreads();
    if (threadIdx.x == 0) {
      int cum = 0, b = 255;
      for (;;) {
        int c = hist[b];
        if (cum + c >= rank || b == 0) break;
        cum += c; b--;
      }
      s_pref = prefix | ((unsigned)b << shift);
      s_rank = rank - cum;
    }
    __syncthreads();
    prefix = s_pref; rank = s_rank;
    __syncthreads();
  }
  if (threadIdx.x == 0) { thr_key[e] = prefix; needed[e] = rank; }
}

__global__ void zero_counters(int* p) {
  if (threadIdx.x < 2 * NE) p[threadIdx.x] = 0;
}

// ---------------- compact selected tokens -> token_idx / scores -------------
__global__ __launch_bounds__(256) void compact_k(const float* __restrict__ probs,
                                                 const unsigned* __restrict__ thr_key,
                                                 const int* __restrict__ needed,
                                                 int* __restrict__ cnt, int* __restrict__ eqc,
                                                 int* __restrict__ tok, float* __restrict__ scr) {
  int gid = blockIdx.x * 256 + threadIdx.x;   // gid = e*NT + t
  int e = gid >> 14, t = gid & (NT - 1);
  float pv = probs[gid];
  unsigned k = __float_as_uint(pv);
  unsigned thr = thr_key[e];
  if (k < thr) return;
  if (k > thr) {
    int slot = atomicAdd(&cnt[e], 1);
    tok[e * CAP + slot] = t; scr[e * CAP + slot] = pv;
  } else {
    int q = atomicAdd(&eqc[e], 1);
    if (q < needed[e]) {
      int slot = atomicAdd(&cnt[e], 1);
      tok[e * CAP + slot] = t; scr[e * CAP + slot] = pv;
    }
  }
}

// ---------------- 128x128 bf16 MFMA GEMM, fused epilogues --------------------
// A: (Mtot,K) bf16 row-major (optionally row-indirect via rowmap)
// BT: per-group (N,K) bf16 row-major, group = m0 >> gshift
// MODE 0: outH[gm*N+gn] = bf16(gelu(acc + bias[gn]))
// MODE 1: outF[gm*N+gn] = acc + bias[gn]
// MODE 2: atomicAdd(outF[tok[gm]*N+gn], (acc + bias[gn]) * scr[gm])
template <int MODE>
__global__ __launch_bounds__(256) void gemm128(
    const bf16* __restrict__ A, int lda, const int* __restrict__ rowmap,
    const bf16* __restrict__ BT, long long bstride, int gshift,
    const float* __restrict__ bias, int bias_stride,
    int N, int K,
    bf16* __restrict__ outH, float* __restrict__ outF,
    const int* __restrict__ tok, const float* __restrict__ scr) {
  __shared__ __attribute__((aligned(16))) bf16 As[128 * 32];
  __shared__ __attribute__((aligned(16))) bf16 Bs[128 * 32];
  int tid = threadIdx.x;
  int m0 = blockIdx.y << 7, n0 = blockIdx.x << 7;
  int grp = m0 >> gshift;
  const bf16* Bp = BT + (size_t)grp * (size_t)bstride;
  const float* bp = bias + (size_t)grp * (size_t)bias_stride;

  int lane = tid & 63, wv = tid >> 6;
  int wr = (wv >> 1) << 6, wc = (wv & 1) << 6;

  // staging: idx (0..511) covers 16B chunk: row = idx>>2, k8 = (idx&3)*8
  int sr = tid >> 2;
  int sk = (tid & 3) << 3;
  int gr0 = m0 + sr, gr1 = m0 + sr + 64;
  int ar0 = rowmap ? rowmap[gr0] : gr0;
  int ar1 = rowmap ? rowmap[gr1] : gr1;
  const bf16* as0 = A + (size_t)ar0 * lda + sk;
  const bf16* as1 = A + (size_t)ar1 * lda + sk;
  const bf16* bs0 = Bp + (size_t)(n0 + sr) * K + sk;
  const bf16* bs1 = Bp + (size_t)(n0 + sr + 64) * K + sk;
  bf16* ad0 = As + tid * 8; bf16* ad1 = As + (tid + 256) * 8;
  bf16* bd0 = Bs + tid * 8; bf16* bd1 = Bs + (tid + 256) * 8;

  v4f acc[4][4] = {};
  int fr = lane & 15, kq = (lane >> 4) << 3;

  for (int k0 = 0; k0 < K; k0 += 32) {
    load_lds16(as0 + k0, ad0);
    load_lds16(as1 + k0, ad1);
    load_lds16(bs0 + k0, bd0);
    load_lds16(bs1 + k0, bd1);
    __syncthreads();
    v8s af[4], bf[4];
#pragma unroll
    for (int i = 0; i < 4; i++) af[i] = *(const v8s*)(As + ((wr + i * 16 + fr) << 5) + kq);
#pragma unroll
    for (int i = 0; i < 4; i++) bf[i] = *(const v8s*)(Bs + ((wc + i * 16 + fr) << 5) + kq);
#pragma unroll
    for (int mi = 0; mi < 4; mi++)
#pragma unroll
      for (int ni = 0; ni < 4; ni++)
        acc[mi][ni] = __builtin_amdgcn_mfma_f32_16x16x32_bf16(af[mi], bf[ni], acc[mi][ni], 0, 0, 0);
    __syncthreads();
  }

  int qr = (lane >> 4) << 2;
#pragma unroll
  for (int mi = 0; mi < 4; mi++) {
#pragma unroll
    for (int r = 0; r < 4; r++) {
      int gm = m0 + wr + mi * 16 + qr + r;
      int trow = 0; float sv = 0.f;
      if (MODE == 2) { trow = tok[gm]; sv = scr[gm]; }
#pragma unroll
      for (int ni = 0; ni < 4; ni++) {
        int gn = n0 + wc + ni * 16 + fr;
        float v = acc[mi][ni][r] + bp[gn];
        if (MODE == 0)      outH[(size_t)gm * N + gn] = __float2bfloat16(gelu_tanh(v));
        else if (MODE == 1) outF[(size_t)gm * N + gn] = v;
        else                atomicAdd(outF + (size_t)trow * N + gn, v * sv);
      }
    }
  }
}

extern "C" void kernel_launch(void* const* d_in, const int* in_sizes, int n_in,
                              void* d_out, int out_size, void* d_ws, size_t ws_size,
                              hipStream_t stream) {
  const float* x   = (const float*)d_in[0];
  const float* gate= (const float*)d_in[1];
  const float* W1  = (const float*)d_in[2];
  const float* b1  = (const float*)d_in[3];
  const float* W2  = (const float*)d_in[4];
  const float* b2  = (const float*)d_in[5];
  const float* Ws1 = (const float*)d_in[6];
  const float* bs1 = (const float*)d_in[7];
  const float* Ws2 = (const float*)d_in[8];
  const float* bs2 = (const float*)d_in[9];
  float* out = (float*)d_out;

  char* w = (char*)d_ws;
  size_t off = 0;
  auto alloc = [&](size_t bytes) {
    void* p = w + off;
    off = (off + bytes + 255) & ~(size_t)255;
    return p;
  };
  bf16* xb    = (bf16*)alloc((size_t)NT * ND * 2);
  bf16* w1T   = (bf16*)alloc((size_t)NE * NH * ND * 2);
  bf16* w2T   = (bf16*)alloc((size_t)NE * ND * NH * 2);
  bf16* ws1T  = (bf16*)alloc((size_t)NH * ND * 2);
  bf16* ws2T  = (bf16*)alloc((size_t)ND * NH * 2);
  bf16* h     = (bf16*)alloc((size_t)NT * NH * 2);
  float* probs= (float*)alloc((size_t)NE * NT * 4);
  unsigned* thr = (unsigned*)alloc(NE * 4);
  int* needed = (int*)alloc(NE * 4);
  int* cnt    = (int*)alloc(2 * NE * 4);   // cnt[0..7], eqc[8..15] contiguous
  int* eqc    = cnt + NE;
  int* tok    = (int*)alloc((size_t)NE * CAP * 4);
  float* scr  = (float*)alloc((size_t)NE * CAP * 4);
  if (off > ws_size) return;  // insufficient workspace -> fail loudly in validation

  // ---- precision conversion (+ weight transpose to N-major) ----
  cvt_bf16<<<2048, 256, 0, stream>>>(x, xb, NT * ND);
  tcvt<<<dim3(NH / 32, ND / 32, NE), 256, 0, stream>>>(W1, w1T, ND, NH);   // (E,D,H)->(E,H,D)
  tcvt<<<dim3(ND / 32, NH / 32, NE), 256, 0, stream>>>(W2, w2T, NH, ND);   // (E,H,D)->(E,D,H)
  tcvt<<<dim3(NH / 32, ND / 32, 1), 256, 0, stream>>>(Ws1, ws1T, ND, NH);
  tcvt<<<dim3(ND / 32, NH / 32, 1), 256, 0, stream>>>(Ws2, ws2T, NH, ND);

  // ---- router + top-k selection ----
  router_k<<<NT / 4, 256, 0, stream>>>(x, gate, probs);
  topk_k<<<NE, 1024, 0, stream>>>(probs, thr, needed);
  zero_counters<<<1, 64, 0, stream>>>(cnt);
  compact_k<<<NE * NT / 256, 256, 0, stream>>>(probs, thr, needed, cnt, eqc, tok, scr);

  // ---- shared expert: h = gelu(x@Ws1+bs1); out = h@Ws2+bs2 (plain store) ----
  gemm128<0><<<dim3(NH / 128, NT / 128), 256, 0, stream>>>(
      xb, ND, nullptr, ws1T, 0, 30, bs1, 0, NH, ND, h, nullptr, nullptr, nullptr);
  gemm128<1><<<dim3(ND / 128, NT / 128), 256, 0, stream>>>(
      h, NH, nullptr, ws2T, 0, 30, bs2, 0, ND, NH, nullptr, out, nullptr, nullptr);

  // ---- routed experts: gather rows via tok, per-expert weights, scatter-add ----
  gemm128<0><<<dim3(NH / 128, NT / 128), 256, 0, stream>>>(
      xb, ND, tok, w1T, (long long)NH * ND, 11, b1, NH, NH, ND, h, nullptr, nullptr, nullptr);
  gemm128<2><<<dim3(ND / 128, NT / 128), 256, 0, stream>>>(
      h, NH, nullptr, w2T, (long long)ND * NH, 11, b2, ND, ND, NH, nullptr, out, tok, scr);
}

// Round 2
// 1049.909 us; speedup vs baseline: 1.4225x; 1.4225x over previous
//
#include <hip/hip_runtime.h>
#include <hip/hip_bf16.h>

using bf16 = __hip_bfloat16;
typedef short v8s __attribute__((ext_vector_type(8)));
typedef float v4f __attribute__((ext_vector_type(4)));

#define NE 8
#define NT 16384
#define ND 1024
#define NH 4096
#define CAP 2048

__device__ __forceinline__ void load_lds16(const void* g, void* s) {
  __builtin_amdgcn_global_load_lds(
      (const __attribute__((address_space(1))) unsigned int*)g,
      (__attribute__((address_space(3))) unsigned int*)s, 16, 0, 0);
}

__device__ __forceinline__ float gelu_tanh(float x) {
  float u = 0.7978845608028654f * (x + 0.044715f * x * x * x);
  float e = __expf(2.0f * u);
  float t = 1.0f - 2.0f / (e + 1.0f);
  return 0.5f * x * (1.0f + t);
}

// ---------------- fp32 -> bf16 elementwise ----------------
__global__ __launch_bounds__(256) void cvt_bf16(const float* __restrict__ s,
                                                bf16* __restrict__ d, int n) {
  for (int i = (blockIdx.x * 256 + threadIdx.x) * 4; i < n; i += gridDim.x * 1024) {
    float4 v = *(const float4*)(s + i);
    bf16 o[4];
    o[0] = __float2bfloat16(v.x); o[1] = __float2bfloat16(v.y);
    o[2] = __float2bfloat16(v.z); o[3] = __float2bfloat16(v.w);
    *(ushort4*)(d + i) = *(ushort4*)o;
  }
}

// ---------------- fp32 (R,C) -> bf16 (C,R), batched over blockIdx.z ----------
__global__ __launch_bounds__(256) void tcvt(const float* __restrict__ src,
                                            bf16* __restrict__ dst, int R, int C) {
  __shared__ float tile[32][33];
  size_t mo = (size_t)blockIdx.z * R * C;
  int c0 = blockIdx.x * 32, r0 = blockIdx.y * 32;
  int tx = threadIdx.x & 31, ty = threadIdx.x >> 5;
  for (int i = ty; i < 32; i += 8)
    tile[i][tx] = src[mo + (size_t)(r0 + i) * C + c0 + tx];
  __syncthreads();
  for (int i = ty; i < 32; i += 8)
    dst[mo + (size_t)(c0 + i) * R + r0 + tx] = __float2bfloat16(tile[tx][i]);
}

// ---------------- router: logits (fp64 accum) + softmax -> probs[E][T] ------
__global__ __launch_bounds__(256) void router_k(const float* __restrict__ x,
                                                const float* __restrict__ gate,
                                                float* __restrict__ probs) {
  int wave = threadIdx.x >> 6, lane = threadIdx.x & 63;
  int t = blockIdx.x * 4 + wave;
  const float* xr = x + (size_t)t * ND;
  double acc[NE];
#pragma unroll
  for (int e = 0; e < NE; e++) acc[e] = 0.0;
  for (int d = lane; d < ND; d += 64) {
    double xv = (double)xr[d];
    const float* g = gate + d * NE;
#pragma unroll
    for (int e = 0; e < NE; e++) acc[e] += xv * (double)g[e];
  }
#pragma unroll
  for (int e = 0; e < NE; e++) {
    double v = acc[e];
#pragma unroll
    for (int off = 32; off > 0; off >>= 1) v += __shfl_xor(v, off);
    acc[e] = v;
  }
  if (lane == 0) {
    float l[NE], m = -1e30f;
#pragma unroll
    for (int e = 0; e < NE; e++) { l[e] = (float)acc[e]; m = fmaxf(m, l[e]); }
    float p[NE], s = 0.f;
#pragma unroll
    for (int e = 0; e < NE; e++) { p[e] = expf(l[e] - m); s += p[e]; }
#pragma unroll
    for (int e = 0; e < NE; e++) probs[e * NT + t] = p[e] / s;
  }
}

// ---------------- per-expert radix select of the 2048th largest prob --------
__global__ __launch_bounds__(1024) void topk_k(const float* __restrict__ probs,
                                               unsigned* __restrict__ thr_key,
                                               int* __restrict__ needed) {
  int e = blockIdx.x;
  const float* p = probs + e * NT;
  __shared__ int hist[256];
  __shared__ unsigned s_pref;
  __shared__ int s_rank;
  unsigned prefix = 0;
  int rank = CAP;
  for (int rd = 0; rd < 4; rd++) {
    int shift = 24 - rd * 8;
    if (threadIdx.x < 256) hist[threadIdx.x] = 0;
    __syncthreads();
    unsigned mask = (rd == 0) ? 0u : (0xFFFFFFFFu << (shift + 8));
    for (int t = threadIdx.x; t < NT; t += 1024) {
      unsigned k = __float_as_uint(p[t]);
      if ((k & mask) == prefix) atomicAdd(&hist[(k >> shift) & 255], 1);
    }
    __syncthreads();
    if (threadIdx.x == 0) {
      int cum = 0, b = 255;
      for (;;) {
        int c = hist[b];
        if (cum + c >= rank || b == 0) break;
        cum += c; b--;
      }
      s_pref = prefix | ((unsigned)b << shift);
      s_rank = rank - cum;
    }
    __syncthreads();
    prefix = s_pref; rank = s_rank;
    __syncthreads();
  }
  if (threadIdx.x == 0) { thr_key[e] = prefix; needed[e] = rank; }
}

__global__ void zero_counters(int* p) {
  if (threadIdx.x < 2 * NE) p[threadIdx.x] = 0;
}

// ---------------- compact selected tokens -> token_idx / scores -------------
__global__ __launch_bounds__(256) void compact_k(const float* __restrict__ probs,
                                                 const unsigned* __restrict__ thr_key,
                                                 const int* __restrict__ needed,
                                                 int* __restrict__ cnt, int* __restrict__ eqc,
                                                 int* __restrict__ tok, float* __restrict__ scr) {
  int gid = blockIdx.x * 256 + threadIdx.x;
  int e = gid >> 14, t = gid & (NT - 1);
  float pv = probs[gid];
  unsigned k = __float_as_uint(pv);
  unsigned thr = thr_key[e];
  if (k < thr) return;
  if (k > thr) {
    int slot = atomicAdd(&cnt[e], 1);
    tok[e * CAP + slot] = t; scr[e * CAP + slot] = pv;
  } else {
    int q = atomicAdd(&eqc[e], 1);
    if (q < needed[e]) {
      int slot = atomicAdd(&cnt[e], 1);
      tok[e * CAP + slot] = t; scr[e * CAP + slot] = pv;
    }
  }
}

// =============== 256x256 8-phase bf16 MFMA GEMM (T2+T3+T4+T5) ===============
// A: (Mtot,K) bf16 row-major (optional row gather via rowmap)
// BT: per-group (N,K) bf16 row-major, group = m0 >> gshift
// MODE 0: outH = bf16(gelu(acc + bias));  MODE 1: outF = acc + bias;
// MODE 2: atomicAdd(outF[tok[gm]*N+gn], (acc+bias)*scr[gm])
#define BAR() __builtin_amdgcn_s_barrier()
#define LGKM0() do { asm volatile("s_waitcnt lgkmcnt(0)" ::: "memory"); \
                     __builtin_amdgcn_sched_barrier(0); } while (0)

template <int MODE>
__global__ __launch_bounds__(512, 2) void gemm256(
    const bf16* __restrict__ A, int lda, const int* __restrict__ rowmap,
    const bf16* __restrict__ BT, long long bstride, int gshift,
    const float* __restrict__ bias, int bias_stride,
    int N, int K,
    bf16* __restrict__ outH, float* __restrict__ outF,
    const int* __restrict__ tok, const float* __restrict__ scr) {
  __shared__ __attribute__((aligned(16))) char lds[131072];
  const int tid = threadIdx.x;
  const int lane = tid & 63, wv = tid >> 6;
  const int wr = wv >> 2, wc = wv & 3;           // 2x4 wave grid
  const int m0 = blockIdx.y << 8, n0 = blockIdx.x << 8;
  const int grp = m0 >> gshift;
  const bf16* Bp = BT + (size_t)grp * (size_t)bstride;
  const float* bp = bias + (size_t)grp * (size_t)bias_stride;
  const int nt = K >> 6;                          // K-tiles of 64

  // ---- staging source pointers (pre-swizzled global cols, linear LDS dest) --
  const int srow = tid >> 3;                      // 0..63
  const int pc = tid & 7;                         // physical 16B chunk in row
  const int gc = pc ^ (srow & 7);                 // swizzled source chunk
  const bf16* srcA[4]; const bf16* srcB[4];
#pragma unroll
  for (int g = 0; g < 4; g++) {
    int am = m0 + g * 64 + srow;
    int ar = rowmap ? rowmap[am] : am;
    srcA[g] = A + (size_t)ar * lda + gc * 8;
    srcB[g] = Bp + (size_t)(n0 + g * 64 + srow) * K + gc * 8;
  }
  auto stageA = [&](int t, int h) {
    if (t < nt) {
      char* d = lds + ((t & 1) * 65536 + h * 16384) + tid * 16;
      load_lds16(srcA[h * 2 + 0] + (size_t)t * 64, d);
      load_lds16(srcA[h * 2 + 1] + (size_t)t * 64, d + 8192);
    }
  };
  auto stageB = [&](int t, int h) {
    if (t < nt) {
      char* d = lds + ((t & 1) * 65536 + 32768 + h * 16384) + tid * 16;
      load_lds16(srcB[h * 2 + 0] + (size_t)t * 64, d);
      load_lds16(srcB[h * 2 + 1] + (size_t)t * 64, d + 8192);
    }
  };

  // ---- fragment read addressing (swizzled ds_read) ----
  const int fr = lane & 15, hi = lane >> 4;       // frag row / k-quarter
  const int xr = fr & 7;
  const int cb0 = ((0 + hi) ^ xr) << 4;           // kk=0 byte col
  const int cb1 = ((4 + hi) ^ xr) << 4;           // kk=1 byte col
  const int arow = ((wr << 7) + fr) << 7;         // (wr*128+fr)*128 bytes
  const int brow = ((wc << 6) + fr) << 7;

  v4f acc[8][4] = {};
  v8s a[4][2], b[4][2];

  // ---- prologue: T0 all 4 halves + T1.B0,B1 ; vmcnt(4) keeps 2 in flight ----
  stageA(0, 0); stageA(0, 1); stageB(0, 0); stageB(0, 1);
  stageB(1, 0); stageB(1, 1);
  asm volatile("s_waitcnt vmcnt(4)" ::: "memory");
  BAR();

#define READ_A(MOFF)                                                         \
  _Pragma("unroll") for (int mi = 0; mi < 4; mi++) {                         \
    a[mi][0] = *(const v8s*)(Ab + arow + ((MOFF) + mi) * 2048 + cb0);        \
    a[mi][1] = *(const v8s*)(Ab + arow + ((MOFF) + mi) * 2048 + cb1);        \
  }
#define READ_B(NI)                                                           \
  { b[NI][0] = *(const v8s*)(Bb + brow + (NI) * 2048 + cb0);                 \
    b[NI][1] = *(const v8s*)(Bb + brow + (NI) * 2048 + cb1); }
#define MFMA_QUAD(MOFF, NOFF)                                                \
  __builtin_amdgcn_s_setprio(1);                                             \
  _Pragma("unroll") for (int kk = 0; kk < 2; kk++)                           \
  _Pragma("unroll") for (int mi = 0; mi < 4; mi++)                           \
  _Pragma("unroll") for (int ni = 0; ni < 2; ni++)                           \
    acc[(MOFF) + mi][(NOFF) + ni] = __builtin_amdgcn_mfma_f32_16x16x32_bf16( \
        a[mi][kk], b[(NOFF) + ni][kk], acc[(MOFF) + mi][(NOFF) + ni], 0, 0, 0); \
  __builtin_amdgcn_s_setprio(0);

  for (int t = 0; t < nt; ++t) {
    const char* Ab = lds + (t & 1) * 65536;
    const char* Bb = Ab + 32768;
    // phase 1: A-low + B-low reads; stage (t+1).A0
    READ_A(0); READ_B(0); READ_B(1);
    stageA(t + 1, 0);
    BAR(); LGKM0();
    MFMA_QUAD(0, 0);
    BAR();
    // phase 2: B-high reads; stage (t+1).A1
    READ_B(2); READ_B(3);
    stageA(t + 1, 1);
    BAR(); LGKM0();
    MFMA_QUAD(0, 2);
    BAR();
    // phase 3: A-high reads; stage (t+2).B0
    READ_A(4);
    stageB(t + 2, 0);
    BAR(); LGKM0();
    MFMA_QUAD(4, 0);
    BAR();
    // phase 4: stage (t+2).B1; counted vmcnt gate for tile t+1
    stageB(t + 2, 1);
    if (t + 2 < nt) { asm volatile("s_waitcnt vmcnt(4)" ::: "memory"); }
    else            { asm volatile("s_waitcnt vmcnt(0)" ::: "memory"); }
    BAR();
    MFMA_QUAD(4, 2);
    BAR();
  }

  // ---- epilogue ----
  float bv[4];
#pragma unroll
  for (int ni = 0; ni < 4; ni++) bv[ni] = bp[n0 + (wc << 6) + ni * 16 + fr];
  const int rbase = m0 + (wr << 7) + (hi << 2);
#pragma unroll
  for (int mi = 0; mi < 8; mi++) {
#pragma unroll
    for (int r = 0; r < 4; r++) {
      int gm = rbase + mi * 16 + r;
      int trow = 0; float sv = 0.f;
      if (MODE == 2) { trow = tok[gm]; sv = scr[gm]; }
#pragma unroll
      for (int ni = 0; ni < 4; ni++) {
        int gn = n0 + (wc << 6) + ni * 16 + fr;
        float v = acc[mi][ni][r] + bv[ni];
        if (MODE == 0)      outH[(size_t)gm * N + gn] = __float2bfloat16(gelu_tanh(v));
        else if (MODE == 1) outF[(size_t)gm * N + gn] = v;
        else                atomicAdd(outF + (size_t)trow * N + gn, v * sv);
      }
    }
  }
}

extern "C" void kernel_launch(void* const* d_in, const int* in_sizes, int n_in,
                              void* d_out, int out_size, void* d_ws, size_t ws_size,
                              hipStream_t stream) {
  const float* x   = (const float*)d_in[0];
  const float* gate= (const float*)d_in[1];
  const float* W1  = (const float*)d_in[2];
  const float* b1  = (const float*)d_in[3];
  const float* W2  = (const float*)d_in[4];
  const float* b2  = (const float*)d_in[5];
  const float* Ws1 = (const float*)d_in[6];
  const float* bs1 = (const float*)d_in[7];
  const float* Ws2 = (const float*)d_in[8];
  const float* bs2 = (const float*)d_in[9];
  float* out = (float*)d_out;

  char* w = (char*)d_ws;
  size_t off = 0;
  auto alloc = [&](size_t bytes) {
    void* p = w + off;
    off = (off + bytes + 255) & ~(size_t)255;
    return p;
  };
  bf16* xb    = (bf16*)alloc((size_t)NT * ND * 2);
  bf16* w1T   = (bf16*)alloc((size_t)NE * NH * ND * 2);
  bf16* w2T   = (bf16*)alloc((size_t)NE * ND * NH * 2);
  bf16* ws1T  = (bf16*)alloc((size_t)NH * ND * 2);
  bf16* ws2T  = (bf16*)alloc((size_t)ND * NH * 2);
  bf16* h     = (bf16*)alloc((size_t)NT * NH * 2);
  float* probs= (float*)alloc((size_t)NE * NT * 4);
  unsigned* thr = (unsigned*)alloc(NE * 4);
  int* needed = (int*)alloc(NE * 4);
  int* cnt    = (int*)alloc(2 * NE * 4);
  int* eqc    = cnt + NE;
  int* tok    = (int*)alloc((size_t)NE * CAP * 4);
  float* scr  = (float*)alloc((size_t)NE * CAP * 4);
  if (off > ws_size) return;

  // ---- precision conversion (+ weight transpose to N-major) ----
  cvt_bf16<<<2048, 256, 0, stream>>>(x, xb, NT * ND);
  tcvt<<<dim3(NH / 32, ND / 32, NE), 256, 0, stream>>>(W1, w1T, ND, NH);
  tcvt<<<dim3(ND / 32, NH / 32, NE), 256, 0, stream>>>(W2, w2T, NH, ND);
  tcvt<<<dim3(NH / 32, ND / 32, 1), 256, 0, stream>>>(Ws1, ws1T, ND, NH);
  tcvt<<<dim3(ND / 32, NH / 32, 1), 256, 0, stream>>>(Ws2, ws2T, NH, ND);

  // ---- router + top-k selection ----
  router_k<<<NT / 4, 256, 0, stream>>>(x, gate, probs);
  topk_k<<<NE, 1024, 0, stream>>>(probs, thr, needed);
  zero_counters<<<1, 64, 0, stream>>>(cnt);
  compact_k<<<NE * NT / 256, 256, 0, stream>>>(probs, thr, needed, cnt, eqc, tok, scr);

  // ---- shared expert ----
  gemm256<0><<<dim3(NH / 256, NT / 256), 512, 0, stream>>>(
      xb, ND, nullptr, ws1T, 0, 30, bs1, 0, NH, ND, h, nullptr, nullptr, nullptr);
  gemm256<1><<<dim3(ND / 256, NT / 256), 512, 0, stream>>>(
      h, NH, nullptr, ws2T, 0, 30, bs2, 0, ND, NH, nullptr, out, nullptr, nullptr);

  // ---- routed experts ----
  gemm256<0><<<dim3(NH / 256, NT / 256), 512, 0, stream>>>(
      xb, ND, tok, w1T, (long long)NH * ND, 11, b1, NH, NH, ND, h, nullptr, nullptr, nullptr);
  gemm256<2><<<dim3(ND / 256, NT / 256), 512, 0, stream>>>(
      h, NH, nullptr, w2T, (long long)ND * NH, 11, b2, ND, ND, NH, nullptr, out, tok, scr);
}

// Round 3
// 855.961 us; speedup vs baseline: 1.7448x; 1.2266x over previous
//
#include <hip/hip_runtime.h>
#include <hip/hip_bf16.h>

using bf16 = __hip_bfloat16;
typedef short v8s __attribute__((ext_vector_type(8)));
typedef float v4f __attribute__((ext_vector_type(4)));

#define NE 8
#define NT 16384
#define ND 1024
#define NH 4096
#define CAP 2048

__device__ __forceinline__ void load_lds16(const void* g, void* s) {
  __builtin_amdgcn_global_load_lds(
      (const __attribute__((address_space(1))) unsigned int*)g,
      (__attribute__((address_space(3))) unsigned int*)s, 16, 0, 0);
}

__device__ __forceinline__ float gelu_tanh(float x) {
  float u = 0.7978845608028654f * (x + 0.044715f * x * x * x);
  float e = __expf(2.0f * u);
  float t = 1.0f - 2.0f / (e + 1.0f);
  return 0.5f * x * (1.0f + t);
}

// ---------------- fp32 -> bf16 elementwise ----------------
__global__ __launch_bounds__(256) void cvt_bf16(const float* __restrict__ s,
                                                bf16* __restrict__ d, int n) {
  for (int i = (blockIdx.x * 256 + threadIdx.x) * 4; i < n; i += gridDim.x * 1024) {
    float4 v = *(const float4*)(s + i);
    bf16 o[4];
    o[0] = __float2bfloat16(v.x); o[1] = __float2bfloat16(v.y);
    o[2] = __float2bfloat16(v.z); o[3] = __float2bfloat16(v.w);
    *(ushort4*)(d + i) = *(ushort4*)o;
  }
}

// ---------------- fp32 (R,C) -> bf16 (C,R), batched over blockIdx.z ----------
__global__ __launch_bounds__(256) void tcvt(const float* __restrict__ src,
                                            bf16* __restrict__ dst, int R, int C) {
  __shared__ float tile[32][33];
  size_t mo = (size_t)blockIdx.z * R * C;
  int c0 = blockIdx.x * 32, r0 = blockIdx.y * 32;
  int tx = threadIdx.x & 31, ty = threadIdx.x >> 5;
  for (int i = ty; i < 32; i += 8)
    tile[i][tx] = src[mo + (size_t)(r0 + i) * C + c0 + tx];
  __syncthreads();
  for (int i = ty; i < 32; i += 8)
    dst[mo + (size_t)(c0 + i) * R + r0 + tx] = __float2bfloat16(tile[tx][i]);
}

// ---------------- router: logits (fp64 accum) + softmax -> probs[E][T] ------
__global__ __launch_bounds__(256) void router_k(const float* __restrict__ x,
                                                const float* __restrict__ gate,
                                                float* __restrict__ probs) {
  int wave = threadIdx.x >> 6, lane = threadIdx.x & 63;
  int t = blockIdx.x * 4 + wave;
  const float* xr = x + (size_t)t * ND;
  double acc[NE];
#pragma unroll
  for (int e = 0; e < NE; e++) acc[e] = 0.0;
  for (int d = lane; d < ND; d += 64) {
    double xv = (double)xr[d];
    const float* g = gate + d * NE;
#pragma unroll
    for (int e = 0; e < NE; e++) acc[e] += xv * (double)g[e];
  }
#pragma unroll
  for (int e = 0; e < NE; e++) {
    double v = acc[e];
#pragma unroll
    for (int off = 32; off > 0; off >>= 1) v += __shfl_xor(v, off);
    acc[e] = v;
  }
  if (lane == 0) {
    float l[NE], m = -1e30f;
#pragma unroll
    for (int e = 0; e < NE; e++) { l[e] = (float)acc[e]; m = fmaxf(m, l[e]); }
    float p[NE], s = 0.f;
#pragma unroll
    for (int e = 0; e < NE; e++) { p[e] = expf(l[e] - m); s += p[e]; }
#pragma unroll
    for (int e = 0; e < NE; e++) probs[e * NT + t] = p[e] / s;
  }
}

// ---------------- per-expert radix select of the 2048th largest prob --------
__global__ __launch_bounds__(1024) void topk_k(const float* __restrict__ probs,
                                               unsigned* __restrict__ thr_key,
                                               int* __restrict__ needed) {
  int e = blockIdx.x;
  const float* p = probs + e * NT;
  __shared__ int hist[256];
  __shared__ unsigned s_pref;
  __shared__ int s_rank;
  unsigned prefix = 0;
  int rank = CAP;
  for (int rd = 0; rd < 4; rd++) {
    int shift = 24 - rd * 8;
    if (threadIdx.x < 256) hist[threadIdx.x] = 0;
    __syncthreads();
    unsigned mask = (rd == 0) ? 0u : (0xFFFFFFFFu << (shift + 8));
    for (int t = threadIdx.x; t < NT; t += 1024) {
      unsigned k = __float_as_uint(p[t]);
      if ((k & mask) == prefix) atomicAdd(&hist[(k >> shift) & 255], 1);
    }
    __syncthreads();
    if (threadIdx.x == 0) {
      int cum = 0, b = 255;
      for (;;) {
        int c = hist[b];
        if (cum + c >= rank || b == 0) break;
        cum += c; b--;
      }
      s_pref = prefix | ((unsigned)b << shift);
      s_rank = rank - cum;
    }
    __syncthreads();
    prefix = s_pref; rank = s_rank;
    __syncthreads();
  }
  if (threadIdx.x == 0) { thr_key[e] = prefix; needed[e] = rank; }
}

__global__ void zero_counters(int* p) {
  if (threadIdx.x < 2 * NE) p[threadIdx.x] = 0;
}

// -------- compact: block-aggregated (1 atomic/class/block, not per-token) ---
// Slot layout: gt tokens -> [0, CAP-needed), eq tokens -> [CAP-needed, CAP).
__global__ __launch_bounds__(256) void compact_k(const float* __restrict__ probs,
                                                 const unsigned* __restrict__ thr_key,
                                                 const int* __restrict__ needed,
                                                 int* __restrict__ cnt, int* __restrict__ eqc,
                                                 int* __restrict__ tok, float* __restrict__ scr) {
  int gid = blockIdx.x * 256 + threadIdx.x;
  int e = gid >> 14, t = gid & (NT - 1);
  float pv = probs[gid];
  unsigned k = __float_as_uint(pv);
  unsigned thr = thr_key[e];
  int nd = needed[e];
  bool gt = k > thr, eq = k == thr;
  unsigned long long mgt = __ballot(gt), meq = __ballot(eq);
  int lane = threadIdx.x & 63, wv = threadIdx.x >> 6;
  __shared__ int wcnt[2][4];
  __shared__ int base[2];
  if (lane == 0) { wcnt[0][wv] = __popcll(mgt); wcnt[1][wv] = __popcll(meq); }
  __syncthreads();
  if (threadIdx.x == 0) {
    int s0 = wcnt[0][0] + wcnt[0][1] + wcnt[0][2] + wcnt[0][3];
    int s1 = wcnt[1][0] + wcnt[1][1] + wcnt[1][2] + wcnt[1][3];
    base[0] = s0 ? atomicAdd(&cnt[e], s0) : 0;
    base[1] = s1 ? atomicAdd(&eqc[e], s1) : 0;
  }
  __syncthreads();
  unsigned long long lm = (1ull << lane) - 1ull;
  if (gt) {
    int p = __popcll(mgt & lm);
    for (int w = 0; w < wv; w++) p += wcnt[0][w];
    int slot = base[0] + p;
    tok[e * CAP + slot] = t; scr[e * CAP + slot] = pv;
  } else if (eq) {
    int q = base[1] + __popcll(meq & lm);
    for (int w = 0; w < wv; w++) q += wcnt[1][w];
    if (q < nd) {
      int slot = (CAP - nd) + q;
      tok[e * CAP + slot] = t; scr[e * CAP + slot] = pv;
    }
  }
}

// ========= 256x256 pipelined bf16 MFMA GEMM: 2 barriers/tile, counted vmcnt ==
#define BAR() __builtin_amdgcn_s_barrier()
#define LGKM0() do { asm volatile("s_waitcnt lgkmcnt(0)" ::: "memory"); \
                     __builtin_amdgcn_sched_barrier(0); } while (0)

template <int MODE>
__global__ __launch_bounds__(512, 2) void gemm256(
    const bf16* __restrict__ A, int lda, const int* __restrict__ rowmap,
    const bf16* __restrict__ BT, long long bstride, int gshift,
    const float* __restrict__ bias, int bias_stride,
    int N, int K,
    bf16* __restrict__ outH, float* __restrict__ outF,
    const int* __restrict__ tok, const float* __restrict__ scr) {
  __shared__ __attribute__((aligned(16))) char lds[131072];
  const int tid = threadIdx.x;
  const int lane = tid & 63, wv = tid >> 6;
  const int wr = wv >> 2, wc = wv & 3;             // 2x4 wave grid
  // XCD-chunked bijective swizzle, y-fast decode (M-tiles == 64 for all uses)
  const int hw = blockIdx.y * gridDim.x + blockIdx.x;
  const int nwg = gridDim.x * gridDim.y;
  const int swz = (hw & 7) * (nwg >> 3) + (hw >> 3);
  const int m0 = (swz & 63) << 8;
  const int n0 = (swz >> 6) << 8;
  const int grp = m0 >> gshift;
  const bf16* Bp = BT + (size_t)grp * (size_t)bstride;
  const float* bp = bias + (size_t)grp * (size_t)bias_stride;
  const int nt = K >> 6;                           // K-tiles of 64

  // ---- staging source pointers (pre-swizzled global cols, linear LDS dest) --
  const int srow = tid >> 3;                       // 0..63
  const int pc = tid & 7;
  const int gc = pc ^ (srow & 7);                  // swizzled source chunk
  const bf16* srcA[4]; const bf16* srcB[4];
#pragma unroll
  for (int g = 0; g < 4; g++) {
    int am = m0 + g * 64 + srow;
    int ar = rowmap ? rowmap[am] : am;
    srcA[g] = A + (size_t)ar * lda + gc * 8;
    srcB[g] = Bp + (size_t)(n0 + g * 64 + srow) * K + gc * 8;
  }
  auto stageA = [&](int t, int h) {
    char* d = lds + ((t & 1) * 65536 + h * 16384) + tid * 16;
    load_lds16(srcA[h * 2 + 0] + (size_t)t * 64, d);
    load_lds16(srcA[h * 2 + 1] + (size_t)t * 64, d + 8192);
  };
  auto stageB = [&](int t, int h) {
    char* d = lds + ((t & 1) * 65536 + 32768 + h * 16384) + tid * 16;
    load_lds16(srcB[h * 2 + 0] + (size_t)t * 64, d);
    load_lds16(srcB[h * 2 + 1] + (size_t)t * 64, d + 8192);
  };

  // ---- fragment read addressing (swizzled ds_read) ----
  const int fr = lane & 15, hi = lane >> 4;
  const int xr = fr & 7;
  const int cb0 = ((0 + hi) ^ xr) << 4;
  const int cb1 = ((4 + hi) ^ xr) << 4;
  const int arow = ((wr << 7) + fr) << 7;
  const int brow = ((wc << 6) + fr) << 7;

  v4f acc[8][4] = {};
  v8s a[4][2], b[4][2];

#define READ_A(BASE, MOFF)                                                    \
  _Pragma("unroll") for (int mi = 0; mi < 4; mi++) {                          \
    a[mi][0] = *(const v8s*)((BASE) + arow + ((MOFF) + mi) * 2048 + cb0);     \
    a[mi][1] = *(const v8s*)((BASE) + arow + ((MOFF) + mi) * 2048 + cb1);     \
  }
#define READ_B(BASE, NI)                                                      \
  { b[NI][0] = *(const v8s*)((BASE) + brow + (NI) * 2048 + cb0);              \
    b[NI][1] = *(const v8s*)((BASE) + brow + (NI) * 2048 + cb1); }
#define MFMA_QUAD(MOFF, NOFF)                                                 \
  __builtin_amdgcn_s_setprio(1);                                              \
  _Pragma("unroll") for (int kk = 0; kk < 2; kk++)                            \
  _Pragma("unroll") for (int mi = 0; mi < 4; mi++)                            \
  _Pragma("unroll") for (int ni = 0; ni < 2; ni++)                            \
    acc[(MOFF) + mi][(NOFF) + ni] = __builtin_amdgcn_mfma_f32_16x16x32_bf16(  \
        a[mi][kk], b[(NOFF) + ni][kk], acc[(MOFF) + mi][(NOFF) + ni], 0, 0, 0); \
  __builtin_amdgcn_s_setprio(0);

  // ---- prologue: stage T0 fully + T1 fully (order A then B per tile) ----
  stageA(0, 0); stageA(0, 1); stageB(0, 0); stageB(0, 1);
  stageA(1, 0); stageA(1, 1); stageB(1, 0); stageB(1, 1);
  asm volatile("s_waitcnt vmcnt(8)" ::: "memory");   // T0 landed; T1 in flight
  BAR();
  {
    const char* Ab0 = lds; const char* Bb0 = lds + 32768;
    READ_A(Ab0, 0); READ_B(Bb0, 0); READ_B(Bb0, 1);
  }

  for (int t = 0; t < nt; ++t) {
    const char* Ab = lds + (t & 1) * 65536;
    const char* Bb = Ab + 32768;
    const char* AbN = lds + ((t + 1) & 1) * 65536;
    const char* BbN = AbN + 32768;
    // P1: consume preloaded A0-3,B0-1
    LGKM0();
    MFMA_QUAD(0, 0);
    READ_B(Bb, 2); READ_B(Bb, 3);
    stageA(t + 1, 0);
    // P2
    LGKM0();
    MFMA_QUAD(0, 2);
    READ_A(Ab, 4);                 // reuse a regs for A4-7
    stageA(t + 1, 1);
    BAR();                         // WAR: all B-frag reads retired before stageB lands
    // P3
    LGKM0();
    MFMA_QUAD(4, 0);
    stageB(t + 2, 0);
    stageB(t + 2, 1);
    // P4: gate tile t+1 (A(t+1) landed; B(t+2) stays in flight)
    asm volatile("s_waitcnt vmcnt(4)" ::: "memory");
    BAR();
    MFMA_QUAD(4, 2);
    READ_A(AbN, 0); READ_B(BbN, 0); READ_B(BbN, 1);   // preload next tile
  }
  asm volatile("s_waitcnt vmcnt(0) lgkmcnt(0)" ::: "memory");

  // ---- epilogue ----
  float bv[4];
#pragma unroll
  for (int ni = 0; ni < 4; ni++) bv[ni] = bp[n0 + (wc << 6) + ni * 16 + fr];
  const int rbase = m0 + (wr << 7) + (hi << 2);
#pragma unroll
  for (int mi = 0; mi < 8; mi++) {
#pragma unroll
    for (int r = 0; r < 4; r++) {
      int gm = rbase + mi * 16 + r;
      int trow = 0; float sv = 0.f;
      if (MODE == 2) { trow = tok[gm]; sv = scr[gm]; }
#pragma unroll
      for (int ni = 0; ni < 4; ni++) {
        int gn = n0 + (wc << 6) + ni * 16 + fr;
        float v = acc[mi][ni][r] + bv[ni];
        if (MODE == 0)      outH[(size_t)gm * N + gn] = __float2bfloat16(gelu_tanh(v));
        else if (MODE == 1) outF[(size_t)gm * N + gn] = v;
        else                atomicAdd(outF + (size_t)trow * N + gn, v * sv);
      }
    }
  }
}

extern "C" void kernel_launch(void* const* d_in, const int* in_sizes, int n_in,
                              void* d_out, int out_size, void* d_ws, size_t ws_size,
                              hipStream_t stream) {
  const float* x   = (const float*)d_in[0];
  const float* gate= (const float*)d_in[1];
  const float* W1  = (const float*)d_in[2];
  const float* b1  = (const float*)d_in[3];
  const float* W2  = (const float*)d_in[4];
  const float* b2  = (const float*)d_in[5];
  const float* Ws1 = (const float*)d_in[6];
  const float* bs1 = (const float*)d_in[7];
  const float* Ws2 = (const float*)d_in[8];
  const float* bs2 = (const float*)d_in[9];
  float* out = (float*)d_out;

  char* w = (char*)d_ws;
  size_t off = 0;
  auto alloc = [&](size_t bytes) {
    void* p = w + off;
    off = (off + bytes + 255) & ~(size_t)255;
    return p;
  };
  bf16* xb    = (bf16*)alloc((size_t)NT * ND * 2);
  bf16* w1T   = (bf16*)alloc((size_t)NE * NH * ND * 2);
  bf16* w2T   = (bf16*)alloc((size_t)NE * ND * NH * 2);
  bf16* ws1T  = (bf16*)alloc((size_t)NH * ND * 2);
  bf16* ws2T  = (bf16*)alloc((size_t)ND * NH * 2);
  bf16* h     = (bf16*)alloc((size_t)NT * NH * 2);
  float* probs= (float*)alloc((size_t)NE * NT * 4);
  unsigned* thr = (unsigned*)alloc(NE * 4);
  int* needed = (int*)alloc(NE * 4);
  int* cnt    = (int*)alloc(2 * NE * 4);
  int* eqc    = cnt + NE;
  int* tok    = (int*)alloc((size_t)NE * CAP * 4);
  float* scr  = (float*)alloc((size_t)NE * CAP * 4);
  if (off > ws_size) return;

  // ---- precision conversion (+ weight transpose to N-major) ----
  cvt_bf16<<<2048, 256, 0, stream>>>(x, xb, NT * ND);
  tcvt<<<dim3(NH / 32, ND / 32, NE), 256, 0, stream>>>(W1, w1T, ND, NH);
  tcvt<<<dim3(ND / 32, NH / 32, NE), 256, 0, stream>>>(W2, w2T, NH, ND);
  tcvt<<<dim3(NH / 32, ND / 32, 1), 256, 0, stream>>>(Ws1, ws1T, ND, NH);
  tcvt<<<dim3(ND / 32, NH / 32, 1), 256, 0, stream>>>(Ws2, ws2T, NH, ND);

  // ---- router + top-k selection ----
  router_k<<<NT / 4, 256, 0, stream>>>(x, gate, probs);
  topk_k<<<NE, 1024, 0, stream>>>(probs, thr, needed);
  zero_counters<<<1, 64, 0, stream>>>(cnt);
  compact_k<<<NE * NT / 256, 256, 0, stream>>>(probs, thr, needed, cnt, eqc, tok, scr);

  // ---- shared expert ----
  gemm256<0><<<dim3(NH / 256, NT / 256), 512, 0, stream>>>(
      xb, ND, nullptr, ws1T, 0, 30, bs1, 0, NH, ND, h, nullptr, nullptr, nullptr);
  gemm256<1><<<dim3(ND / 256, NT / 256), 512, 0, stream>>>(
      h, NH, nullptr, ws2T, 0, 30, bs2, 0, ND, NH, nullptr, out, nullptr, nullptr);

  // ---- routed experts ----
  gemm256<0><<<dim3(NH / 256, NT / 256), 512, 0, stream>>>(
      xb, ND, tok, w1T, (long long)NH * ND, 11, b1, NH, NH, ND, h, nullptr, nullptr, nullptr);
  gemm256<2><<<dim3(ND / 256, NT / 256), 512, 0, stream>>>(
      h, NH, nullptr, w2T, (long long)ND * NH, 11, b2, ND, ND, NH, nullptr, out, tok, scr);
}

// Round 4
// 845.441 us; speedup vs baseline: 1.7665x; 1.0124x over previous
//
#include <hip/hip_runtime.h>
#include <hip/hip_bf16.h>

using bf16 = __hip_bfloat16;
typedef short v8s __attribute__((ext_vector_type(8)));
typedef float v4f __attribute__((ext_vector_type(4)));

#define NE 8
#define NT 16384
#define ND 1024
#define NH 4096
#define CAP 2048

__device__ __forceinline__ void load_lds16(const void* g, void* s) {
  __builtin_amdgcn_global_load_lds(
      (const __attribute__((address_space(1))) unsigned int*)g,
      (__attribute__((address_space(3))) unsigned int*)s, 16, 0, 0);
}

__device__ __forceinline__ float gelu_tanh(float x) {
  float u = 0.7978845608028654f * (x + 0.044715f * x * x * x);
  float e = __expf(2.0f * u);
  float t = 1.0f - 2.0f / (e + 1.0f);
  return 0.5f * x * (1.0f + t);
}

// ---------------- fp32 -> bf16 elementwise ----------------
__global__ __launch_bounds__(256) void cvt_bf16(const float* __restrict__ s,
                                                bf16* __restrict__ d, int n) {
  for (int i = (blockIdx.x * 256 + threadIdx.x) * 4; i < n; i += gridDim.x * 1024) {
    float4 v = *(const float4*)(s + i);
    bf16 o[4];
    o[0] = __float2bfloat16(v.x); o[1] = __float2bfloat16(v.y);
    o[2] = __float2bfloat16(v.z); o[3] = __float2bfloat16(v.w);
    *(ushort4*)(d + i) = *(ushort4*)o;
  }
}

// ---------------- fp32 (R,C) -> bf16 (C,R), batched over blockIdx.z ----------
__global__ __launch_bounds__(256) void tcvt(const float* __restrict__ src,
                                            bf16* __restrict__ dst, int R, int C) {
  __shared__ float tile[32][33];
  size_t mo = (size_t)blockIdx.z * R * C;
  int c0 = blockIdx.x * 32, r0 = blockIdx.y * 32;
  int tx = threadIdx.x & 31, ty = threadIdx.x >> 5;
  for (int i = ty; i < 32; i += 8)
    tile[i][tx] = src[mo + (size_t)(r0 + i) * C + c0 + tx];
  __syncthreads();
  for (int i = ty; i < 32; i += 8)
    dst[mo + (size_t)(c0 + i) * R + r0 + tx] = __float2bfloat16(tile[tx][i]);
}

// ---------------- router: logits (fp64 accum) + softmax -> probs[E][T] ------
__global__ __launch_bounds__(256) void router_k(const float* __restrict__ x,
                                                const float* __restrict__ gate,
                                                float* __restrict__ probs) {
  int wave = threadIdx.x >> 6, lane = threadIdx.x & 63;
  int t = blockIdx.x * 4 + wave;
  const float* xr = x + (size_t)t * ND;
  double acc[NE];
#pragma unroll
  for (int e = 0; e < NE; e++) acc[e] = 0.0;
  for (int d = lane; d < ND; d += 64) {
    double xv = (double)xr[d];
    const float* g = gate + d * NE;
#pragma unroll
    for (int e = 0; e < NE; e++) acc[e] += xv * (double)g[e];
  }
#pragma unroll
  for (int e = 0; e < NE; e++) {
    double v = acc[e];
#pragma unroll
    for (int off = 32; off > 0; off >>= 1) v += __shfl_xor(v, off);
    acc[e] = v;
  }
  if (lane == 0) {
    float l[NE], m = -1e30f;
#pragma unroll
    for (int e = 0; e < NE; e++) { l[e] = (float)acc[e]; m = fmaxf(m, l[e]); }
    float p[NE], s = 0.f;
#pragma unroll
    for (int e = 0; e < NE; e++) { p[e] = expf(l[e] - m); s += p[e]; }
#pragma unroll
    for (int e = 0; e < NE; e++) probs[e * NT + t] = p[e] / s;
  }
}

// ---------------- per-expert radix select of the 2048th largest prob --------
__global__ __launch_bounds__(1024) void topk_k(const float* __restrict__ probs,
                                               unsigned* __restrict__ thr_key,
                                               int* __restrict__ needed) {
  int e = blockIdx.x;
  const float* p = probs + e * NT;
  __shared__ int hist[256];
  __shared__ unsigned s_pref;
  __shared__ int s_rank;
  unsigned prefix = 0;
  int rank = CAP;
  for (int rd = 0; rd < 4; rd++) {
    int shift = 24 - rd * 8;
    if (threadIdx.x < 256) hist[threadIdx.x] = 0;
    __syncthreads();
    unsigned mask = (rd == 0) ? 0u : (0xFFFFFFFFu << (shift + 8));
    for (int t = threadIdx.x; t < NT; t += 1024) {
      unsigned k = __float_as_uint(p[t]);
      if ((k & mask) == prefix) atomicAdd(&hist[(k >> shift) & 255], 1);
    }
    __syncthreads();
    if (threadIdx.x == 0) {
      int cum = 0, b = 255;
      for (;;) {
        int c = hist[b];
        if (cum + c >= rank || b == 0) break;
        cum += c; b--;
      }
      s_pref = prefix | ((unsigned)b << shift);
      s_rank = rank - cum;
    }
    __syncthreads();
    prefix = s_pref; rank = s_rank;
    __syncthreads();
  }
  if (threadIdx.x == 0) { thr_key[e] = prefix; needed[e] = rank; }
}

__global__ void zero_counters(int* p) {
  if (threadIdx.x < 2 * NE) p[threadIdx.x] = 0;
}

// -------- compact: block-aggregated (1 atomic/class/block, not per-token) ---
__global__ __launch_bounds__(256) void compact_k(const float* __restrict__ probs,
                                                 const unsigned* __restrict__ thr_key,
                                                 const int* __restrict__ needed,
                                                 int* __restrict__ cnt, int* __restrict__ eqc,
                                                 int* __restrict__ tok, float* __restrict__ scr) {
  int gid = blockIdx.x * 256 + threadIdx.x;
  int e = gid >> 14, t = gid & (NT - 1);
  float pv = probs[gid];
  unsigned k = __float_as_uint(pv);
  unsigned thr = thr_key[e];
  int nd = needed[e];
  bool gt = k > thr, eq = k == thr;
  unsigned long long mgt = __ballot(gt), meq = __ballot(eq);
  int lane = threadIdx.x & 63, wv = threadIdx.x >> 6;
  __shared__ int wcnt[2][4];
  __shared__ int base[2];
  if (lane == 0) { wcnt[0][wv] = __popcll(mgt); wcnt[1][wv] = __popcll(meq); }
  __syncthreads();
  if (threadIdx.x == 0) {
    int s0 = wcnt[0][0] + wcnt[0][1] + wcnt[0][2] + wcnt[0][3];
    int s1 = wcnt[1][0] + wcnt[1][1] + wcnt[1][2] + wcnt[1][3];
    base[0] = s0 ? atomicAdd(&cnt[e], s0) : 0;
    base[1] = s1 ? atomicAdd(&eqc[e], s1) : 0;
  }
  __syncthreads();
  unsigned long long lm = (1ull << lane) - 1ull;
  if (gt) {
    int p = __popcll(mgt & lm);
    for (int w = 0; w < wv; w++) p += wcnt[0][w];
    int slot = base[0] + p;
    tok[e * CAP + slot] = t; scr[e * CAP + slot] = pv;
  } else if (eq) {
    int q = base[1] + __popcll(meq & lm);
    for (int w = 0; w < wv; w++) q += wcnt[1][w];
    if (q < nd) {
      int slot = (CAP - nd) + q;
      tok[e * CAP + slot] = t; scr[e * CAP + slot] = pv;
    }
  }
}

// === 256x256 bf16 MFMA GEMM: 2-phase-early ds_reads + counted lgkm/vm waits ==
#define BAR() __builtin_amdgcn_s_barrier()
#define SBAR0() __builtin_amdgcn_sched_barrier(0)

template <int MODE>
__global__ __launch_bounds__(512, 2) void gemm256(
    const bf16* __restrict__ A, int lda, const int* __restrict__ rowmap,
    const bf16* __restrict__ BT, long long bstride, int gshift,
    const float* __restrict__ bias, int bias_stride,
    int N, int K,
    bf16* __restrict__ outH, float* __restrict__ outF,
    const int* __restrict__ tok, const float* __restrict__ scr) {
  __shared__ __attribute__((aligned(16))) char lds[131072];
  const int tid = threadIdx.x;
  const int lane = tid & 63, wv = tid >> 6;
  const int wr = wv >> 2, wc = wv & 3;             // 2x4 wave grid
  const int hw = blockIdx.y * gridDim.x + blockIdx.x;
  const int nwg = gridDim.x * gridDim.y;
  const int swz = (hw & 7) * (nwg >> 3) + (hw >> 3);
  const int m0 = (swz & 63) << 8;
  const int n0 = (swz >> 6) << 8;
  const int grp = m0 >> gshift;
  const bf16* Bp = BT + (size_t)grp * (size_t)bstride;
  const float* bp = bias + (size_t)grp * (size_t)bias_stride;
  const int nt = K >> 6;                           // K-tiles of 64

  // ---- staging (pre-swizzled global source cols, linear LDS dest) ----
  const int srow = tid >> 3;
  const int pc = tid & 7;
  const int gc = pc ^ (srow & 7);
  const bf16* srcA[4]; const bf16* srcB[4];
#pragma unroll
  for (int g = 0; g < 4; g++) {
    int am = m0 + g * 64 + srow;
    int ar = rowmap ? rowmap[am] : am;
    srcA[g] = A + (size_t)ar * lda + gc * 8;
    srcB[g] = Bp + (size_t)(n0 + g * 64 + srow) * K + gc * 8;
  }
  auto stageA = [&](int t, int h) {
    char* d = lds + ((t & 1) * 65536 + h * 16384) + tid * 16;
    load_lds16(srcA[h * 2 + 0] + (size_t)t * 64, d);
    load_lds16(srcA[h * 2 + 1] + (size_t)t * 64, d + 8192);
  };
  auto stageB = [&](int t, int h) {
    char* d = lds + ((t & 1) * 65536 + 32768 + h * 16384) + tid * 16;
    load_lds16(srcB[h * 2 + 0] + (size_t)t * 64, d);
    load_lds16(srcB[h * 2 + 1] + (size_t)t * 64, d + 8192);
  };

  // ---- fragment read addressing (swizzled ds_read) ----
  const int fr = lane & 15, hi = lane >> 4;
  const int xr = fr & 7;
  const int cb0 = ((0 + hi) ^ xr) << 4;
  const int cb1 = ((4 + hi) ^ xr) << 4;
  const int arow = ((wr << 7) + fr) << 7;
  const int brow = ((wc << 6) + fr) << 7;

  v4f acc[8][4] = {};
  v8s a03[4][2], a47[4][2], b01[2][2], b23[2][2];

#define R_A03(BASE)                                                           \
  _Pragma("unroll") for (int mi = 0; mi < 4; mi++) {                          \
    a03[mi][0] = *(const v8s*)((BASE) + arow + mi * 2048 + cb0);              \
    a03[mi][1] = *(const v8s*)((BASE) + arow + mi * 2048 + cb1);              \
  }
#define R_A47(BASE)                                                           \
  _Pragma("unroll") for (int mi = 0; mi < 4; mi++) {                          \
    a47[mi][0] = *(const v8s*)((BASE) + arow + (4 + mi) * 2048 + cb0);        \
    a47[mi][1] = *(const v8s*)((BASE) + arow + (4 + mi) * 2048 + cb1);        \
  }
#define R_B01(BASE)                                                           \
  _Pragma("unroll") for (int ni = 0; ni < 2; ni++) {                          \
    b01[ni][0] = *(const v8s*)((BASE) + brow + ni * 2048 + cb0);              \
    b01[ni][1] = *(const v8s*)((BASE) + brow + ni * 2048 + cb1);              \
  }
#define R_B23(BASE)                                                           \
  _Pragma("unroll") for (int ni = 0; ni < 2; ni++) {                          \
    b23[ni][0] = *(const v8s*)((BASE) + brow + (2 + ni) * 2048 + cb0);        \
    b23[ni][1] = *(const v8s*)((BASE) + brow + (2 + ni) * 2048 + cb1);        \
  }
#define MFMA_Q(AB, BB, MOFF, NOFF)                                            \
  __builtin_amdgcn_s_setprio(1);                                              \
  _Pragma("unroll") for (int kk = 0; kk < 2; kk++)                            \
  _Pragma("unroll") for (int mi = 0; mi < 4; mi++)                            \
  _Pragma("unroll") for (int ni = 0; ni < 2; ni++)                            \
    acc[(MOFF) + mi][(NOFF) + ni] = __builtin_amdgcn_mfma_f32_16x16x32_bf16(  \
        AB[mi][kk], BB[ni][kk], acc[(MOFF) + mi][(NOFF) + ni], 0, 0, 0);      \
  __builtin_amdgcn_s_setprio(0);

  // ---- prologue: stage A(0),B(0),B(1); reads for tile 0 ----
  stageA(0, 0); stageA(0, 1); stageB(0, 0); stageB(0, 1);
  if (nt > 1) { stageB(1, 0); stageB(1, 1); }
  if (nt > 1) { asm volatile("s_waitcnt vmcnt(4)" ::: "memory"); }
  else        { asm volatile("s_waitcnt vmcnt(0)" ::: "memory"); }
  BAR();
  {
    const char* Ab0 = lds; const char* Bb0 = lds + 32768;
    R_A03(Ab0); R_B01(Bb0); R_B23(Bb0); R_A47(Ab0);
  }

  for (int t = 0; t < nt; ++t) {
    const char* AbN = lds + ((t + 1) & 1) * 65536;
    const char* BbN = AbN + 32768;
    // P1: consume a03 x b01 (reads issued at P4 of t-1; 12 newer still fly)
    asm volatile("s_waitcnt lgkmcnt(12)" ::: "memory"); SBAR0();
    MFMA_Q(a03, b01, 0, 0);
    if (t + 1 < nt) stageA(t + 1, 0);
    // P2: consume a03 x b23 (b23 done when <=8 remain)
    asm volatile("s_waitcnt lgkmcnt(8)" ::: "memory"); SBAR0();
    MFMA_Q(a03, b23, 0, 2);
    if (t + 1 < nt) stageA(t + 1, 1);
    BAR();                      // all waves' tile-t B reads retired -> stageB safe
    // P3: consume a47 x b01
    asm volatile("s_waitcnt lgkmcnt(0)" ::: "memory"); SBAR0();
    MFMA_Q(a47, b01, 4, 0);
    if (t + 2 < nt) stageB(t + 2, 0);
    // P4: gate A(t+1); issue next-tile reads around the last MFMA quad
    if (t + 2 < nt) stageB(t + 2, 1);
    if (t + 2 < nt) { asm volatile("s_waitcnt vmcnt(4)" ::: "memory"); }
    else            { asm volatile("s_waitcnt vmcnt(0)" ::: "memory"); }
    BAR();
    if (t + 1 < nt) { R_A03(AbN); R_B01(BbN); }
    MFMA_Q(a47, b23, 4, 2);
    if (t + 1 < nt) { R_B23(BbN); R_A47(AbN); }
  }
  asm volatile("s_waitcnt vmcnt(0) lgkmcnt(0)" ::: "memory");

  // ---- epilogue ----
  float bv[4];
#pragma unroll
  for (int ni = 0; ni < 4; ni++) bv[ni] = bp[n0 + (wc << 6) + ni * 16 + fr];
  const int rbase = m0 + (wr << 7) + (hi << 2);
#pragma unroll
  for (int mi = 0; mi < 8; mi++) {
#pragma unroll
    for (int r = 0; r < 4; r++) {
      int gm = rbase + mi * 16 + r;
      int trow = 0; float sv = 0.f;
      if (MODE == 2) { trow = tok[gm]; sv = scr[gm]; }
#pragma unroll
      for (int ni = 0; ni < 4; ni++) {
        int gn = n0 + (wc << 6) + ni * 16 + fr;
        float v = acc[mi][ni][r] + bv[ni];
        if (MODE == 0)      outH[(size_t)gm * N + gn] = __float2bfloat16(gelu_tanh(v));
        else if (MODE == 1) outF[(size_t)gm * N + gn] = v;
        else                atomicAdd(outF + (size_t)trow * N + gn, v * sv);
      }
    }
  }
}

extern "C" void kernel_launch(void* const* d_in, const int* in_sizes, int n_in,
                              void* d_out, int out_size, void* d_ws, size_t ws_size,
                              hipStream_t stream) {
  const float* x   = (const float*)d_in[0];
  const float* gate= (const float*)d_in[1];
  const float* W1  = (const float*)d_in[2];
  const float* b1  = (const float*)d_in[3];
  const float* W2  = (const float*)d_in[4];
  const float* b2  = (const float*)d_in[5];
  const float* Ws1 = (const float*)d_in[6];
  const float* bs1 = (const float*)d_in[7];
  const float* Ws2 = (const float*)d_in[8];
  const float* bs2 = (const float*)d_in[9];
  float* out = (float*)d_out;

  char* w = (char*)d_ws;
  size_t off = 0;
  auto alloc = [&](size_t bytes) {
    void* p = w + off;
    off = (off + bytes + 255) & ~(size_t)255;
    return p;
  };
  bf16* xb    = (bf16*)alloc((size_t)NT * ND * 2);
  bf16* w1T   = (bf16*)alloc((size_t)NE * NH * ND * 2);
  bf16* w2T   = (bf16*)alloc((size_t)NE * ND * NH * 2);
  bf16* ws1T  = (bf16*)alloc((size_t)NH * ND * 2);
  bf16* ws2T  = (bf16*)alloc((size_t)ND * NH * 2);
  bf16* h     = (bf16*)alloc((size_t)NT * NH * 2);
  float* probs= (float*)alloc((size_t)NE * NT * 4);
  unsigned* thr = (unsigned*)alloc(NE * 4);
  int* needed = (int*)alloc(NE * 4);
  int* cnt    = (int*)alloc(2 * NE * 4);
  int* eqc    = cnt + NE;
  int* tok    = (int*)alloc((size_t)NE * CAP * 4);
  float* scr  = (float*)alloc((size_t)NE * CAP * 4);
  if (off > ws_size) return;

  // ---- precision conversion (+ weight transpose to N-major) ----
  cvt_bf16<<<2048, 256, 0, stream>>>(x, xb, NT * ND);
  tcvt<<<dim3(NH / 32, ND / 32, NE), 256, 0, stream>>>(W1, w1T, ND, NH);
  tcvt<<<dim3(ND / 32, NH / 32, NE), 256, 0, stream>>>(W2, w2T, NH, ND);
  tcvt<<<dim3(NH / 32, ND / 32, 1), 256, 0, stream>>>(Ws1, ws1T, ND, NH);
  tcvt<<<dim3(ND / 32, NH / 32, 1), 256, 0, stream>>>(Ws2, ws2T, NH, ND);

  // ---- router + top-k selection ----
  router_k<<<NT / 4, 256, 0, stream>>>(x, gate, probs);
  topk_k<<<NE, 1024, 0, stream>>>(probs, thr, needed);
  zero_counters<<<1, 64, 0, stream>>>(cnt);
  compact_k<<<NE * NT / 256, 256, 0, stream>>>(probs, thr, needed, cnt, eqc, tok, scr);

  // ---- shared expert ----
  gemm256<0><<<dim3(NH / 256, NT / 256), 512, 0, stream>>>(
      xb, ND, nullptr, ws1T, 0, 30, bs1, 0, NH, ND, h, nullptr, nullptr, nullptr);
  gemm256<1><<<dim3(ND / 256, NT / 256), 512, 0, stream>>>(
      h, NH, nullptr, ws2T, 0, 30, bs2, 0, ND, NH, nullptr, out, nullptr, nullptr);

  // ---- routed experts ----
  gemm256<0><<<dim3(NH / 256, NT / 256), 512, 0, stream>>>(
      xb, ND, tok, w1T, (long long)NH * ND, 11, b1, NH, NH, ND, h, nullptr, nullptr, nullptr);
  gemm256<2><<<dim3(ND / 256, NT / 256), 512, 0, stream>>>(
      h, NH, nullptr, w2T, (long long)ND * NH, 11, b2, ND, ND, NH, nullptr, out, tok, scr);
}